// Round 14
// baseline (114.369 us; speedup 1.0000x reference)
//
#include <hip/hip_runtime.h>

#define B_ 4
#define N_ 8192
#define D_ 128
#define K_ 32

typedef short short8 __attribute__((ext_vector_type(8)));
typedef float f32x4 __attribute__((ext_vector_type(4)));
typedef int i32x4v __attribute__((ext_vector_type(4)));
typedef int i32x2v __attribute__((ext_vector_type(2)));

__device__ __forceinline__ unsigned short f2bf(float f) {
  unsigned int u = __float_as_uint(f);
  u += 0x7FFFu + ((u >> 16) & 1u);   // round-to-nearest-even
  return (unsigned short)(u >> 16);
}
__device__ __forceinline__ float bf2f(unsigned short h) {
  return __uint_as_float(((unsigned int)h) << 16);
}
// Non-temporal (streaming) access helpers: keep L2 for the gather's V rows.
__device__ __forceinline__ float4 nt_load_f4(const float* p) {
  i32x4v v = __builtin_nontemporal_load(reinterpret_cast<const i32x4v*>(p));
  return *reinterpret_cast<float4*>(&v);
}
__device__ __forceinline__ ushort4 nt_load_u4(const unsigned short* p) {
  i32x2v v = __builtin_nontemporal_load(reinterpret_cast<const i32x2v*>(p));
  return *reinterpret_cast<ushort4*>(&v);
}
__device__ __forceinline__ void nt_store_f4(float* p, float4 v) {
  __builtin_nontemporal_store(*reinterpret_cast<i32x4v*>(&v),
                              reinterpret_cast<i32x4v*>(p));
}

// ---------- K0: Wt[col256][floc128] bf16, col256 = is_v*128 + d ------------
__global__ __launch_bounds__(256) void cvt_w_kernel(const float* __restrict__ W,
                                                    unsigned short* __restrict__ Wt) {
  int e = blockIdx.x * 256 + threadIdx.x;      // 32768 elements, coalesced read
  int d = e & 127, fglob = e >> 7;
  int is_v = fglob >> 7, floc = fglob & 127;
  Wt[(is_v * 128 + d) * 128 + floc] = f2bf(W[e]);
}

// ---------- K1: P[row][256] bf16 = [X*W1 | X*W2]  (M=64/block, 512 blocks) --
__global__ __launch_bounds__(512) void gemm_kernel(
    const float* __restrict__ x, const unsigned short* __restrict__ Wt,
    unsigned short* __restrict__ P) {
  __shared__ __align__(16) unsigned char in_tile[64 * 256];   // 16 KB staging
  __shared__ __align__(16) unsigned char out_tile[64 * 512];  // 32 KB epilogue

  const int t = threadIdx.x, wave = t >> 6, lane = t & 63;
  const int l15 = lane & 15, kg = lane >> 4;
  const long row0 = (long)blockIdx.x * 64;

  // stage 64x128 f32 -> bf16 LDS (byte ^= (row&7)<<4); nt: x is single-use here
  #pragma unroll
  for (int i = 0; i < 4; ++i) {
    int idx = t + i * 512;                     // 2048 float4 chunks
    int row = idx >> 5, cs = idx & 31;
    float4 v = nt_load_f4(x + (row0 + row) * D_ + cs * 4);
    ushort4 o;
    o.x = f2bf(v.x); o.y = f2bf(v.y); o.z = f2bf(v.z); o.w = f2bf(v.w);
    *reinterpret_cast<ushort4*>(
        in_tile + ((row * 256 + cs * 8) ^ ((row & 7) << 4))) = o;
  }

  // B fragments from Wt: 2 coltiles x 4 k-steps, each one 16B load
  const int halfw = wave & 3, is_v = wave >> 2;
  short8 bw[2][4];
  #pragma unroll
  for (int tt = 0; tt < 2; ++tt) {
    const int col = is_v * 128 + halfw * 32 + tt * 16 + l15;
    #pragma unroll
    for (int ks = 0; ks < 4; ++ks)
      bw[tt][ks] = *reinterpret_cast<const short8*>(
          Wt + col * 128 + ks * 32 + kg * 8);
  }
  __syncthreads();

  f32x4 acc[4][2];
  #pragma unroll
  for (int r = 0; r < 4; ++r)
    #pragma unroll
    for (int tt = 0; tt < 2; ++tt)
      acc[r][tt] = (f32x4){0.f, 0.f, 0.f, 0.f};

  #pragma unroll
  for (int ks = 0; ks < 4; ++ks) {
    #pragma unroll
    for (int r = 0; r < 4; ++r) {
      int row = r * 16 + l15;
      short8 af = *reinterpret_cast<const short8*>(
          in_tile + ((row * 256 + ks * 64 + kg * 16) ^ ((row & 7) << 4)));
      acc[r][0] = __builtin_amdgcn_mfma_f32_16x16x32_bf16(af, bw[0][ks], acc[r][0], 0, 0, 0);
      acc[r][1] = __builtin_amdgcn_mfma_f32_16x16x32_bf16(af, bw[1][ks], acc[r][1], 0, 0, 0);
    }
  }

  // acc -> out_tile (bf16, swizzled); then coalesced 16B stores
  #pragma unroll
  for (int r = 0; r < 4; ++r)
    #pragma unroll
    for (int tt = 0; tt < 2; ++tt) {
      const int col = is_v * 128 + halfw * 32 + tt * 16 + l15;
      #pragma unroll
      for (int i = 0; i < 4; ++i) {
        int row = r * 16 + kg * 4 + i;
        *reinterpret_cast<unsigned short*>(
            out_tile + ((row * 512 + col * 2) ^ ((row & 7) << 4))) =
            f2bf(acc[r][tt][i]);
      }
    }
  __syncthreads();

  #pragma unroll
  for (int p = 0; p < 4; ++p) {
    int idx = t + p * 512;
    int row = idx >> 5, cb = (idx & 31) * 16;
    uint4 v = *reinterpret_cast<const uint4*>(
        out_tile + ((row * 512 + cb) ^ ((row & 7) << 4)));
    *reinterpret_cast<uint4*>(P + (row0 + row) * 256 + (cb >> 1)) = v;
  }
}

// ---------- K2: out[n] = LN(gelu(U[n] + mean_k V[adj[n,k]] + b) + x[n]) -----
// Half-wave parallel (2 nodes/wave-instr); V gather loads CACHEABLE, all
// single-use streams (adj, U, x, out) NON-TEMPORAL so V stays L2-resident.
__global__ __launch_bounds__(256) void gather_kernel(
    const int* __restrict__ adj, const unsigned short* __restrict__ P,
    const float* __restrict__ x, const float* __restrict__ bias,
    const float* __restrict__ gamma, const float* __restrict__ beta,
    float* __restrict__ out) {
  const int t = threadIdx.x;
  const int wave = t >> 6, lane = t & 63;
  const int l31 = lane & 31, hs = lane & 32;
  // XCD swizzle (2048 = 8*256): each XCD gets a contiguous half-batch
  const int vblk = ((blockIdx.x & 7) << 8) + (blockIdx.x >> 3);
  const int nb0 = vblk * 16 + wave * 4;
  const int b = nb0 >> 13;
  const unsigned int* pd = (const unsigned int*)P;     // row stride 128 dwords
  const unsigned int* vb_dw = pd + (size_t)b * N_ * 128 + 64 + l31 * 2;
  const int c0 = l31 * 4;
  const float4 bi = *reinterpret_cast<const float4*>(bias + c0);
  const float4 ga = *reinterpret_cast<const float4*>(gamma + c0);
  const float4 be = *reinterpret_cast<const float4*>(beta + c0);

  #pragma unroll
  for (int j = 0; j < 2; ++j) {
    const int nb = nb0 + j * 2;                // halves handle nb, nb+1
    const int gn = nb + (lane >> 5);
    const int av = __builtin_nontemporal_load(adj + (size_t)nb * K_ + lane);
    float a0 = 0.f, a1 = 0.f, a2 = 0.f, a3 = 0.f;
    #pragma unroll
    for (int k = 0; k < K_; ++k) {
      int rowk = __shfl(av, hs | k, 64);       // half-local broadcast
      ushort4 v = *reinterpret_cast<const ushort4*>(vb_dw + (size_t)rowk * 128);
      a0 += bf2f(v.x); a1 += bf2f(v.y); a2 += bf2f(v.z); a3 += bf2f(v.w);
    }
    const ushort4 ud = nt_load_u4(
        reinterpret_cast<const unsigned short*>(pd + (size_t)gn * 128 + l31 * 2));
    const float4 xv = nt_load_f4(x + (size_t)gn * D_ + c0);
    float h0 = bf2f(ud.x) + a0 * 0.03125f + bi.x;
    float h1 = bf2f(ud.y) + a1 * 0.03125f + bi.y;
    float h2 = bf2f(ud.z) + a2 * 0.03125f + bi.z;
    float h3 = bf2f(ud.w) + a3 * 0.03125f + bi.w;
    h0 = 0.5f * h0 * (1.f + erff(h0 * 0.70710678118f));
    h1 = 0.5f * h1 * (1.f + erff(h1 * 0.70710678118f));
    h2 = 0.5f * h2 * (1.f + erff(h2 * 0.70710678118f));
    h3 = 0.5f * h3 * (1.f + erff(h3 * 0.70710678118f));
    const float y0 = h0 + xv.x, y1 = h1 + xv.y;
    const float y2 = h2 + xv.z, y3 = h3 + xv.w;
    float s = y0 + y1 + y2 + y3;
    float sq = y0 * y0 + y1 * y1 + y2 * y2 + y3 * y3;
    #pragma unroll
    for (int off = 1; off < 32; off <<= 1) {   // reduce within 32-lane half
      s  += __shfl_xor(s, off, 64);
      sq += __shfl_xor(sq, off, 64);
    }
    const float mu   = s * (1.f / 128.f);
    const float rstd = rsqrtf(sq * (1.f / 128.f) - mu * mu + 1e-5f);
    float4 o;
    o.x = (y0 - mu) * rstd * ga.x + be.x;
    o.y = (y1 - mu) * rstd * ga.y + be.y;
    o.z = (y2 - mu) * rstd * ga.z + be.z;
    o.w = (y3 - mu) * rstd * ga.w + be.w;
    nt_store_f4(out + (size_t)gn * D_ + c0, o);
  }
}

// ---------------- fallback (no workspace): monolithic f32 path --------------
__global__ __launch_bounds__(512) void fused_f32_kernel(
    const float* __restrict__ x, const int* __restrict__ adj,
    const float* __restrict__ W, const float* __restrict__ bias,
    const float* __restrict__ gamma, const float* __restrict__ beta,
    float* __restrict__ out) {
  __shared__ __align__(16) unsigned char smem[40960];
  unsigned char* in_tile = smem;
  int* adj_lds = (int*)(smem + 32768);
  float* y = (float*)smem;
  const int t = threadIdx.x, wave = t >> 6, lane = t & 63;
  const int l15 = lane & 15, kg = lane >> 4;
  const int vid = (blockIdx.x & 7) * 64 + (blockIdx.x >> 3);
  const int bidx = vid >> 7;
  const long row0 = (long)bidx * N_ + (vid & 127) * 64;
  #pragma unroll
  for (int i = 0; i < 4; ++i)
    adj_lds[t + i * 512] = adj[row0 * K_ + t + i * 512];
  #pragma unroll
  for (int i = 0; i < 4; ++i) {
    int idx = t + i * 512;
    int row = idx >> 5, cp = (idx & 31) * 4;
    float4 v = *reinterpret_cast<const float4*>(x + (row0 + row) * D_ + cp);
    ushort4 o;
    o.x = f2bf(v.x); o.y = f2bf(v.y); o.z = f2bf(v.z); o.w = f2bf(v.w);
    *reinterpret_cast<ushort4*>(in_tile + row * 512 + ((2 * cp) ^ ((row & 7) << 4))) = o;
  }
  __syncthreads();
  {
    const int g = t & 31, rb = t >> 5, c0 = g * 4;
    #pragma unroll
    for (int batch = 0; batch < 4; ++batch) {
      int row = rb + batch * 16;
      const int* ap = adj_lds + row * K_;
      float a0 = 0, a1 = 0, a2 = 0, a3 = 0;
      for (int k = 0; k < K_; ++k) {
        float4 v = *reinterpret_cast<const float4*>(x + ((long)bidx * N_ + ap[k]) * D_ + c0);
        a0 += v.x; a1 += v.y; a2 += v.z; a3 += v.w;
      }
      ushort4 m;
      m.x = f2bf(a0 * 0.03125f); m.y = f2bf(a1 * 0.03125f);
      m.z = f2bf(a2 * 0.03125f); m.w = f2bf(a3 * 0.03125f);
      *reinterpret_cast<ushort4*>(in_tile + row * 512 +
                                  ((2 * (D_ + c0)) ^ ((row & 7) << 4))) = m;
    }
  }
  __syncthreads();
  const int dl = (wave << 4) + l15;
  f32x4 acc[4];
  #pragma unroll
  for (int r = 0; r < 4; ++r) acc[r] = (f32x4){0.f, 0.f, 0.f, 0.f};
  #pragma unroll
  for (int ks = 0; ks < 8; ++ks) {
    short8 bwk;
    #pragma unroll
    for (int j = 0; j < 8; ++j)
      bwk[j] = (short)f2bf(W[(ks * 32 + kg * 8 + j) * D_ + dl]);
    #pragma unroll
    for (int r = 0; r < 4; ++r) {
      int row = r * 16 + l15;
      short8 af = *reinterpret_cast<const short8*>(
          in_tile + row * 512 + ((2 * (ks * 32 + kg * 8)) ^ ((row & 7) << 4)));
      acc[r] = __builtin_amdgcn_mfma_f32_16x16x32_bf16(af, bwk, acc[r], 0, 0, 0);
    }
  }
  __syncthreads();
  const float bv = bias[dl];
  #pragma unroll
  for (int r = 0; r < 4; ++r)
    #pragma unroll
    for (int i = 0; i < 4; ++i) {
      int row = r * 16 + kg * 4 + i;
      float h = acc[r][i] + bv;
      float ge = 0.5f * h * (1.f + erff(h * 0.70710678118f));
      y[row * 132 + dl] = ge + x[(row0 + row) * D_ + dl];
    }
  __syncthreads();
  {
    const int row = t >> 3, l8 = t & 7;
    const float* yr = y + row * 132 + l8 * 16;
    float4 v[4];
    float s = 0.f, sq = 0.f;
    #pragma unroll
    for (int i = 0; i < 4; ++i) {
      v[i] = *reinterpret_cast<const float4*>(yr + i * 4);
      s += v[i].x + v[i].y + v[i].z + v[i].w;
      sq += v[i].x * v[i].x + v[i].y * v[i].y + v[i].z * v[i].z + v[i].w * v[i].w;
    }
    #pragma unroll
    for (int off = 1; off < 8; off <<= 1) {
      s += __shfl_xor(s, off, 64);
      sq += __shfl_xor(sq, off, 64);
    }
    const float mu = s * (1.f / 128.f);
    const float rstd = rsqrtf(sq * (1.f / 128.f) - mu * mu + 1e-5f);
    float* orow = out + (row0 + row) * D_ + l8 * 16;
    #pragma unroll
    for (int i = 0; i < 4; ++i) {
      float4 g = *reinterpret_cast<const float4*>(gamma + l8 * 16 + i * 4);
      float4 bb = *reinterpret_cast<const float4*>(beta + l8 * 16 + i * 4);
      float4 o;
      o.x = (v[i].x - mu) * rstd * g.x + bb.x;
      o.y = (v[i].y - mu) * rstd * g.y + bb.y;
      o.z = (v[i].z - mu) * rstd * g.z + bb.z;
      o.w = (v[i].w - mu) * rstd * g.w + bb.w;
      *reinterpret_cast<float4*>(orow + i * 4) = o;
    }
  }
}

extern "C" void kernel_launch(void* const* d_in, const int* in_sizes, int n_in,
                              void* d_out, int out_size, void* d_ws, size_t ws_size,
                              hipStream_t stream) {
  const float* x     = (const float*)d_in[0];
  const int*   adj   = (const int*)d_in[1];
  const float* W     = (const float*)d_in[2];
  const float* bias  = (const float*)d_in[3];
  const float* gamma = (const float*)d_in[4];
  const float* beta  = (const float*)d_in[5];
  float* out = (float*)d_out;

  const size_t p_bytes  = (size_t)B_ * N_ * 256 * 2;  // 16 MB bf16 [U|V]
  const size_t wt_bytes = (size_t)256 * 128 * 2;      // 64 KB bf16 Wt

  if (ws_size >= p_bytes + wt_bytes) {
    unsigned short* P  = (unsigned short*)d_ws;
    unsigned short* Wt = (unsigned short*)((char*)d_ws + p_bytes);
    cvt_w_kernel<<<dim3(128), dim3(256), 0, stream>>>(W, Wt);
    gemm_kernel<<<dim3((B_ * N_) / 64), dim3(512), 0, stream>>>(x, Wt, P);
    gather_kernel<<<dim3(2048), dim3(256), 0, stream>>>(
        adj, P, x, bias, gamma, beta, out);
  } else {
    fused_f32_kernel<<<dim3((B_ * N_) / 64), dim3(512), 0, stream>>>(
        x, adj, W, bias, gamma, beta, out);
  }
}

// Round 15
// 104.045 us; speedup vs baseline: 1.0992x; 1.0992x over previous
//
#include <hip/hip_runtime.h>

#define B_ 4
#define N_ 8192
#define D_ 128
#define K_ 32

typedef short short8 __attribute__((ext_vector_type(8)));
typedef float f32x4 __attribute__((ext_vector_type(4)));
typedef float floatx2 __attribute__((ext_vector_type(2)));

__device__ __forceinline__ unsigned short f2bf(float f) {
  unsigned int u = __float_as_uint(f);
  u += 0x7FFFu + ((u >> 16) & 1u);   // round-to-nearest-even
  return (unsigned short)(u >> 16);
}
__device__ __forceinline__ float bf2f(unsigned short h) {
  return __uint_as_float(((unsigned int)h) << 16);
}

// ---------- K0: Wt[col256][floc128] bf16, col256 = is_v*128 + d ------------
__global__ __launch_bounds__(256) void cvt_w_kernel(const float* __restrict__ W,
                                                    unsigned short* __restrict__ Wt) {
  int e = blockIdx.x * 256 + threadIdx.x;      // 32768 elements, coalesced read
  int d = e & 127, fglob = e >> 7;
  int is_v = fglob >> 7, floc = fglob & 127;
  Wt[(is_v * 128 + d) * 128 + floc] = f2bf(W[e]);
}

// ---------- K1: U[row][128] bf16 = X*W1 ; V[row][128] fp8 = X*W2 ------------
// M=64/block, 512 blocks, 8 waves (0-3 -> U cols, 4-7 -> V cols).
__global__ __launch_bounds__(512) void gemm_kernel(
    const float* __restrict__ x, const unsigned short* __restrict__ Wt,
    unsigned short* __restrict__ U, unsigned char* __restrict__ V) {
  __shared__ __align__(16) unsigned char in_tile[64 * 256];   // 16 KB staging
  __shared__ __align__(16) unsigned char out_u[64 * 256];     // 16 KB bf16
  __shared__ __align__(16) unsigned char out_v[64 * 128];     //  8 KB fp8

  const int t = threadIdx.x, wave = t >> 6, lane = t & 63;
  const int l15 = lane & 15, kg = lane >> 4;
  const long row0 = (long)blockIdx.x * 64;

  // stage 64x128 f32 -> bf16 LDS (byte ^= (row&7)<<4)
  #pragma unroll
  for (int i = 0; i < 4; ++i) {
    int idx = t + i * 512;                     // 2048 float4 chunks
    int row = idx >> 5, cs = idx & 31;
    float4 v = *reinterpret_cast<const float4*>(x + (row0 + row) * D_ + cs * 4);
    ushort4 o;
    o.x = f2bf(v.x); o.y = f2bf(v.y); o.z = f2bf(v.z); o.w = f2bf(v.w);
    *reinterpret_cast<ushort4*>(
        in_tile + ((row * 256 + cs * 8) ^ ((row & 7) << 4))) = o;
  }

  // B fragments from Wt: 2 coltiles x 4 k-steps, each one 16B load
  const int halfw = wave & 3, is_v = wave >> 2;
  short8 bw[2][4];
  #pragma unroll
  for (int tt = 0; tt < 2; ++tt) {
    const int col = is_v * 128 + halfw * 32 + tt * 16 + l15;
    #pragma unroll
    for (int ks = 0; ks < 4; ++ks)
      bw[tt][ks] = *reinterpret_cast<const short8*>(
          Wt + col * 128 + ks * 32 + kg * 8);
  }
  __syncthreads();

  f32x4 acc[4][2];
  #pragma unroll
  for (int r = 0; r < 4; ++r)
    #pragma unroll
    for (int tt = 0; tt < 2; ++tt)
      acc[r][tt] = (f32x4){0.f, 0.f, 0.f, 0.f};

  #pragma unroll
  for (int ks = 0; ks < 4; ++ks) {
    #pragma unroll
    for (int r = 0; r < 4; ++r) {
      int row = r * 16 + l15;
      short8 af = *reinterpret_cast<const short8*>(
          in_tile + ((row * 256 + ks * 64 + kg * 16) ^ ((row & 7) << 4)));
      acc[r][0] = __builtin_amdgcn_mfma_f32_16x16x32_bf16(af, bw[0][ks], acc[r][0], 0, 0, 0);
      acc[r][1] = __builtin_amdgcn_mfma_f32_16x16x32_bf16(af, bw[1][ks], acc[r][1], 0, 0, 0);
    }
  }

  // epilogue to LDS: U half -> bf16 [64][256B], V half -> fp8 [64][128B]
  #pragma unroll
  for (int r = 0; r < 4; ++r)
    #pragma unroll
    for (int tt = 0; tt < 2; ++tt) {
      const int col = halfw * 32 + tt * 16 + l15;   // 0..127 local
      #pragma unroll
      for (int i = 0; i < 4; ++i) {
        int row = r * 16 + kg * 4 + i;
        if (!is_v) {
          *reinterpret_cast<unsigned short*>(
              out_u + ((row * 256 + col * 2) ^ ((row & 7) << 4))) =
              f2bf(acc[r][tt][i]);
        } else {
          int p8 = __builtin_amdgcn_cvt_pk_fp8_f32(acc[r][tt][i], acc[r][tt][i], 0, false);
          out_v[(row * 128 + col) ^ ((row & 7) << 4)] = (unsigned char)(p8 & 0xFF);
        }
      }
    }
  __syncthreads();

  // coalesced stores: U 16KB = 1024 uint4 (2 rounds), V 8KB = 512 uint4 (1)
  #pragma unroll
  for (int p = 0; p < 2; ++p) {
    int idx = t + p * 512;
    int row = idx >> 4, cb = (idx & 15) * 16;
    uint4 v = *reinterpret_cast<const uint4*>(
        out_u + ((row * 256 + cb) ^ ((row & 7) << 4)));
    *reinterpret_cast<uint4*>(
        reinterpret_cast<unsigned char*>(U) + (row0 + row) * 256 + cb) = v;
  }
  {
    int row = t >> 3, cb = (t & 7) * 16;
    uint4 v = *reinterpret_cast<const uint4*>(
        out_v + ((row * 128 + cb) ^ ((row & 7) << 4)));
    *reinterpret_cast<uint4*>(V + (row0 + row) * 128 + cb) = v;
  }
}

// ---------- K2: out[n] = LN(gelu(U[n] + mean_k V[adj[n,k]] + b) + x[n]) -----
// 2048 blocks x 256 thr; half-wave parallel (2 nodes per wave instr).
// V row = 128B fp8 = ONE cache line; lane owns 4 cols (1 dword of V).
__global__ __launch_bounds__(256) void gather_kernel(
    const int* __restrict__ adj, const unsigned short* __restrict__ U,
    const unsigned char* __restrict__ V, const float* __restrict__ x,
    const float* __restrict__ bias, const float* __restrict__ gamma,
    const float* __restrict__ beta, float* __restrict__ out) {
  const int t = threadIdx.x;
  const int wave = t >> 6, lane = t & 63;
  const int l31 = lane & 31, hs = lane & 32;
  // XCD swizzle (2048 = 8*256): each XCD gets a contiguous half-batch
  const int vblk = ((blockIdx.x & 7) << 8) + (blockIdx.x >> 3);
  const int nb0 = vblk * 16 + wave * 4;
  const int b = nb0 >> 13;
  const unsigned int* vb_dw =
      reinterpret_cast<const unsigned int*>(V + (size_t)b * N_ * 128) + l31;
  const int c0 = l31 * 4;
  const float4 bi = *reinterpret_cast<const float4*>(bias + c0);
  const float4 ga = *reinterpret_cast<const float4*>(gamma + c0);
  const float4 be = *reinterpret_cast<const float4*>(beta + c0);

  #pragma unroll
  for (int j = 0; j < 2; ++j) {
    const int nb = nb0 + j * 2;                // halves handle nb, nb+1
    const int gn = nb + (lane >> 5);
    const int av = adj[(size_t)nb * K_ + lane];
    float a0 = 0.f, a1 = 0.f, a2 = 0.f, a3 = 0.f;
    #pragma unroll
    for (int k = 0; k < K_; ++k) {
      int rowk = __shfl(av, hs | k, 64);       // half-local broadcast
      unsigned int v = vb_dw[(size_t)rowk * 32];
      floatx2 lo = __builtin_amdgcn_cvt_pk_f32_fp8((int)v, false);
      floatx2 hi = __builtin_amdgcn_cvt_pk_f32_fp8((int)v, true);
      a0 += lo[0]; a1 += lo[1]; a2 += hi[0]; a3 += hi[1];
    }
    const ushort4 ud = *reinterpret_cast<const ushort4*>(U + (size_t)gn * 128 + c0);
    const float4 xv = *reinterpret_cast<const float4*>(x + (size_t)gn * D_ + c0);
    float h0 = bf2f(ud.x) + a0 * 0.03125f + bi.x;
    float h1 = bf2f(ud.y) + a1 * 0.03125f + bi.y;
    float h2 = bf2f(ud.z) + a2 * 0.03125f + bi.z;
    float h3 = bf2f(ud.w) + a3 * 0.03125f + bi.w;
    h0 = 0.5f * h0 * (1.f + erff(h0 * 0.70710678118f));
    h1 = 0.5f * h1 * (1.f + erff(h1 * 0.70710678118f));
    h2 = 0.5f * h2 * (1.f + erff(h2 * 0.70710678118f));
    h3 = 0.5f * h3 * (1.f + erff(h3 * 0.70710678118f));
    const float y0 = h0 + xv.x, y1 = h1 + xv.y;
    const float y2 = h2 + xv.z, y3 = h3 + xv.w;
    float s = y0 + y1 + y2 + y3;
    float sq = y0 * y0 + y1 * y1 + y2 * y2 + y3 * y3;
    #pragma unroll
    for (int off = 1; off < 32; off <<= 1) {   // reduce within 32-lane half
      s  += __shfl_xor(s, off, 64);
      sq += __shfl_xor(sq, off, 64);
    }
    const float mu   = s * (1.f / 128.f);
    const float rstd = rsqrtf(sq * (1.f / 128.f) - mu * mu + 1e-5f);
    float4 o;
    o.x = (y0 - mu) * rstd * ga.x + be.x;
    o.y = (y1 - mu) * rstd * ga.y + be.y;
    o.z = (y2 - mu) * rstd * ga.z + be.z;
    o.w = (y3 - mu) * rstd * ga.w + be.w;
    *reinterpret_cast<float4*>(out + (size_t)gn * D_ + c0) = o;
  }
}

// ---------------- fallback (no workspace): monolithic f32 path --------------
__global__ __launch_bounds__(512) void fused_f32_kernel(
    const float* __restrict__ x, const int* __restrict__ adj,
    const float* __restrict__ W, const float* __restrict__ bias,
    const float* __restrict__ gamma, const float* __restrict__ beta,
    float* __restrict__ out) {
  __shared__ __align__(16) unsigned char smem[40960];
  unsigned char* in_tile = smem;
  int* adj_lds = (int*)(smem + 32768);
  float* y = (float*)smem;
  const int t = threadIdx.x, wave = t >> 6, lane = t & 63;
  const int l15 = lane & 15, kg = lane >> 4;
  const int vid = (blockIdx.x & 7) * 64 + (blockIdx.x >> 3);
  const int bidx = vid >> 7;
  const long row0 = (long)bidx * N_ + (vid & 127) * 64;
  #pragma unroll
  for (int i = 0; i < 4; ++i)
    adj_lds[t + i * 512] = adj[row0 * K_ + t + i * 512];
  #pragma unroll
  for (int i = 0; i < 4; ++i) {
    int idx = t + i * 512;
    int row = idx >> 5, cp = (idx & 31) * 4;
    float4 v = *reinterpret_cast<const float4*>(x + (row0 + row) * D_ + cp);
    ushort4 o;
    o.x = f2bf(v.x); o.y = f2bf(v.y); o.z = f2bf(v.z); o.w = f2bf(v.w);
    *reinterpret_cast<ushort4*>(in_tile + row * 512 + ((2 * cp) ^ ((row & 7) << 4))) = o;
  }
  __syncthreads();
  {
    const int g = t & 31, rb = t >> 5, c0 = g * 4;
    #pragma unroll
    for (int batch = 0; batch < 4; ++batch) {
      int row = rb + batch * 16;
      const int* ap = adj_lds + row * K_;
      float a0 = 0, a1 = 0, a2 = 0, a3 = 0;
      for (int k = 0; k < K_; ++k) {
        float4 v = *reinterpret_cast<const float4*>(x + ((long)bidx * N_ + ap[k]) * D_ + c0);
        a0 += v.x; a1 += v.y; a2 += v.z; a3 += v.w;
      }
      ushort4 m;
      m.x = f2bf(a0 * 0.03125f); m.y = f2bf(a1 * 0.03125f);
      m.z = f2bf(a2 * 0.03125f); m.w = f2bf(a3 * 0.03125f);
      *reinterpret_cast<ushort4*>(in_tile + row * 512 +
                                  ((2 * (D_ + c0)) ^ ((row & 7) << 4))) = m;
    }
  }
  __syncthreads();
  const int dl = (wave << 4) + l15;
  f32x4 acc[4];
  #pragma unroll
  for (int r = 0; r < 4; ++r) acc[r] = (f32x4){0.f, 0.f, 0.f, 0.f};
  #pragma unroll
  for (int ks = 0; ks < 8; ++ks) {
    short8 bwk;
    #pragma unroll
    for (int j = 0; j < 8; ++j)
      bwk[j] = (short)f2bf(W[(ks * 32 + kg * 8 + j) * D_ + dl]);
    #pragma unroll
    for (int r = 0; r < 4; ++r) {
      int row = r * 16 + l15;
      short8 af = *reinterpret_cast<const short8*>(
          in_tile + row * 512 + ((2 * (ks * 32 + kg * 8)) ^ ((row & 7) << 4)));
      acc[r] = __builtin_amdgcn_mfma_f32_16x16x32_bf16(af, bwk, acc[r], 0, 0, 0);
    }
  }
  __syncthreads();
  const float bv = bias[dl];
  #pragma unroll
  for (int r = 0; r < 4; ++r)
    #pragma unroll
    for (int i = 0; i < 4; ++i) {
      int row = r * 16 + kg * 4 + i;
      float h = acc[r][i] + bv;
      float ge = 0.5f * h * (1.f + erff(h * 0.70710678118f));
      y[row * 132 + dl] = ge + x[(row0 + row) * D_ + dl];
    }
  __syncthreads();
  {
    const int row = t >> 3, l8 = t & 7;
    const float* yr = y + row * 132 + l8 * 16;
    float4 v[4];
    float s = 0.f, sq = 0.f;
    #pragma unroll
    for (int i = 0; i < 4; ++i) {
      v[i] = *reinterpret_cast<const float4*>(yr + i * 4);
      s += v[i].x + v[i].y + v[i].z + v[i].w;
      sq += v[i].x * v[i].x + v[i].y * v[i].y + v[i].z * v[i].z + v[i].w * v[i].w;
    }
    #pragma unroll
    for (int off = 1; off < 8; off <<= 1) {
      s += __shfl_xor(s, off, 64);
      sq += __shfl_xor(sq, off, 64);
    }
    const float mu = s * (1.f / 128.f);
    const float rstd = rsqrtf(sq * (1.f / 128.f) - mu * mu + 1e-5f);
    float* orow = out + (row0 + row) * D_ + l8 * 16;
    #pragma unroll
    for (int i = 0; i < 4; ++i) {
      float4 g = *reinterpret_cast<const float4*>(gamma + l8 * 16 + i * 4);
      float4 bb = *reinterpret_cast<const float4*>(beta + l8 * 16 + i * 4);
      float4 o;
      o.x = (v[i].x - mu) * rstd * g.x + bb.x;
      o.y = (v[i].y - mu) * rstd * g.y + bb.y;
      o.z = (v[i].z - mu) * rstd * g.z + bb.z;
      o.w = (v[i].w - mu) * rstd * g.w + bb.w;
      *reinterpret_cast<float4*>(orow + i * 4) = o;
    }
  }
}

extern "C" void kernel_launch(void* const* d_in, const int* in_sizes, int n_in,
                              void* d_out, int out_size, void* d_ws, size_t ws_size,
                              hipStream_t stream) {
  const float* x     = (const float*)d_in[0];
  const int*   adj   = (const int*)d_in[1];
  const float* W     = (const float*)d_in[2];
  const float* bias  = (const float*)d_in[3];
  const float* gamma = (const float*)d_in[4];
  const float* beta  = (const float*)d_in[5];
  float* out = (float*)d_out;

  const size_t u_bytes  = (size_t)B_ * N_ * D_ * 2;   // 8 MB bf16 U
  const size_t v_bytes  = (size_t)B_ * N_ * D_;       // 4 MB fp8  V
  const size_t wt_bytes = (size_t)256 * 128 * 2;      // 64 KB bf16 Wt

  if (ws_size >= u_bytes + v_bytes + wt_bytes) {
    unsigned short* U  = (unsigned short*)d_ws;
    unsigned char*  V  = (unsigned char*)d_ws + u_bytes;
    unsigned short* Wt = (unsigned short*)((char*)d_ws + u_bytes + v_bytes);
    cvt_w_kernel<<<dim3(128), dim3(256), 0, stream>>>(W, Wt);
    gemm_kernel<<<dim3((B_ * N_) / 64), dim3(512), 0, stream>>>(x, Wt, U, V);
    gather_kernel<<<dim3(2048), dim3(256), 0, stream>>>(
        adj, U, V, x, bias, gamma, beta, out);
  } else {
    fused_f32_kernel<<<dim3((B_ * N_) / 64), dim3(512), 0, stream>>>(
        x, adj, W, bias, gamma, beta, out);
  }
}